// Round 6
// baseline (370.043 us; speedup 1.0000x reference)
//
#include <hip/hip_runtime.h>
#include <hip/hip_cooperative_groups.h>
#include <math.h>

namespace cg = cooperative_groups;

#define NB 8
#define NC 256
#define HS 64
#define WSM 64
#define HL 512
#define WL 512
#define NK 21
#define PS (HS*WSM)     /* 4096 */
#define PL (HL*WL)      /* 262144 */

#define WT_ELEMS (NK*NC)            /* 5376 */
#define GRID 512                    /* 2 blocks/CU guaranteed resident (51 KB LDS) */
#define NTILE (NB*(PL/4)/256)       /* 2048 out tiles */

typedef float fx4 __attribute__((ext_vector_type(4)));

// LDS union: fused phase needs ~50 KB, out phase ~16.6 KB (disjoint lifetimes,
// separated by grid.sync()).
union SMem {
    struct {
        float sWt[NC*22];      // 22528 B transposed W, stride 22
        float tmp[3][WL];      // 6144 B vertical-pass scratch
        float sA[3][64];       // 768 B
        float red[4][NK][64];  // 21504 B
    } f;
    struct {
        float lq[64*64];       // 16384 B qpart staging
        float sq[NK*3];
    } o;
};

// Single cooperative kernel:
//  phase 1 (all 512 blocks): W staging + separable bilinear adjoint from x
//    + logits (4-wave c-split) + softmax + q-partials -> qpart[b*64+h][64]
//  grid.sync()
//  phase 2: out tiles grid-strided (4 per block): reduce qpart[b] -> sq,
//    out[b,k,p] = sum_c x[b,c,p]*sq[k,c]
__global__ __launch_bounds__(256, 2) void k_all(
    const float* __restrict__ fm, const float* __restrict__ Wc,
    const float* __restrict__ bc, const float* __restrict__ x,
    float* __restrict__ qpart, float* __restrict__ out)
{
    __shared__ SMem S;
    int blk = blockIdx.x;
    int tid = threadIdx.x;
    int lane = tid & 63;
    int wv   = tid >> 6;                      // 0..3

    // ---------------- phase 1: fused adjoint + softmax + q-partials ----------
    {
        int swz = (blk & 7) * 64 + (blk >> 3);   // XCD k owns image b=k
        int b = swz >> 6;
        int h = swz & 63;
        int p = h * 64 + lane;

        // all waves: stage W transposed (coalesced read, 2-way LDS alias = free)
        for (int i = tid; i < WT_ELEMS; i += 256) {
            int k = i >> 8;                   // Wc is [k][c] row-major
            int c = i & 255;
            S.f.sWt[c*22 + k] = Wc[i];
        }

        const float scale = 63.0f / 511.0f;
        const float inv_scale = 511.0f / 63.0f;

        // waves 0..2: adjoint for channel wv at small-row h
        if (wv < 3) {
            int Ylo = max(0,    (int)floorf((h - 1) * inv_scale) - 1);
            int Yhi = min(HL-1, (int)ceilf ((h + 1) * inv_scale) + 1);
            const float* xc = x + (size_t)(b*3 + wv) * PL;
            fx4 acc0 = {0.f,0.f,0.f,0.f}, acc1 = {0.f,0.f,0.f,0.f};
            for (int Y = Ylo; Y <= Yhi; ++Y) {
                float fs = Y * scale;
                int i0 = (int)fs; if (i0 > HS-1) i0 = HS-1;
                float f = fs - (float)i0;
                int i1 = min(i0 + 1, HS-1);
                float wt = (i0 == h ? 1.f - f : 0.f) + (i1 == h ? f : 0.f);
                const fx4* xr = (const fx4*)(xc + (size_t)Y * WL);
                acc0 += wt * xr[lane];
                acc1 += wt * xr[lane + 64];
            }
            fx4* t4 = (fx4*)S.f.tmp[wv];
            t4[lane]      = acc0;
            t4[lane + 64] = acc1;
            // horizontal (same-wave DS ordering, no barrier needed):
            const int w_ = lane;
            int Xlo = max(0,    (int)floorf((w_ - 1) * inv_scale) - 1);
            int Xhi = min(WL-1, (int)ceilf ((w_ + 1) * inv_scale) + 1);
            float a = 0.f;
            for (int X = Xlo; X <= Xhi; ++X) {
                float fs = X * scale;
                int i0 = (int)fs; if (i0 > WSM-1) i0 = WSM-1;
                float f = fs - (float)i0;
                int i1 = min(i0 + 1, WSM-1);
                float wt = (i0 == w_ ? 1.f - f : 0.f) + (i1 == w_ ? f : 0.f);
                a = fmaf(wt, S.f.tmp[wv][X], a);
            }
            S.f.sA[wv][lane] = a;
        }

        __syncthreads();                      // sWt ready (and sA ordered)

        float part[NK];
        #pragma unroll
        for (int k = 0; k < NK; ++k) part[k] = 0.f;

        const float* fmb = fm + (size_t)b * NC * PS + (size_t)(wv * 64) * PS + p;
        #pragma unroll 8
        for (int cc = 0; cc < 64; ++cc) {
            float v = __builtin_nontemporal_load(fmb + (size_t)cc * PS);
            const float* w = S.f.sWt + (wv * 64 + cc) * 22; // uniform -> broadcast
            #pragma unroll
            for (int k = 0; k < NK; ++k) part[k] = fmaf(v, w[k], part[k]);
        }

        #pragma unroll
        for (int k = 0; k < NK; ++k) S.f.red[wv][k][lane] = part[k];
        __syncthreads();

        float logit[NK];
        #pragma unroll
        for (int k = 0; k < NK; ++k)
            logit[k] = bc[k] + ((S.f.red[0][k][lane] + S.f.red[1][k][lane])
                              + (S.f.red[2][k][lane] + S.f.red[3][k][lane]));

        float m = logit[0];
        #pragma unroll
        for (int k = 1; k < NK; ++k) m = fmaxf(m, logit[k]);
        float s = 0.f;
        #pragma unroll
        for (int k = 0; k < NK; ++k) { logit[k] = __expf(logit[k] - m); s += logit[k]; }
        float inv = 1.f / s;

        float a0 = S.f.sA[0][lane], a1 = S.f.sA[1][lane], a2 = S.f.sA[2][lane];

        float* qb = qpart + (size_t)(b*64 + h) * 64;
        for (int k = wv; k < NK; k += 4) {    // k-split across the 4 waves
            float sv = logit[k] * inv;
            float r0 = sv * a0, r1 = sv * a1, r2 = sv * a2;
            #pragma unroll
            for (int off = 32; off; off >>= 1) {
                r0 += __shfl_down(r0, off);
                r1 += __shfl_down(r1, off);
                r2 += __shfl_down(r2, off);
            }
            if (lane == 0) {
                qb[k*3 + 0] = r0;
                qb[k*3 + 1] = r1;
                qb[k*3 + 2] = r2;
            }
        }
    }

    // ---------------- grid-wide barrier (device-scope visibility) ------------
    __threadfence();
    cg::this_grid().sync();
    __threadfence();

    // ---------------- phase 2: out tiles, 4 per block ------------------------
    for (int t = blk; t < NTILE; t += GRID) {
        int b    = t >> 8;                    // 256 tiles per image
        int tile = t & 255;

        const fx4* qp4 = (const fx4*)(qpart + (size_t)b * 64 * 64);
        fx4* lq4 = (fx4*)S.o.lq;
        #pragma unroll
        for (int j = 0; j < 4; ++j) lq4[tid + j*256] = qp4[tid + j*256];
        __syncthreads();
        if (tid < NK*3) {
            float s = 0.f;
            for (int j = 0; j < 64; ++j) s += S.o.lq[j*64 + tid];
            S.o.sq[tid] = s * (1.0f / (float)PL);
        }
        __syncthreads();

        int p4 = tile * 256 + tid;            // fx4 index within image
        const fx4* xb = (const fx4*)(x + (size_t)b * 3 * PL);
        fx4 x0 = xb[p4];
        fx4 x1 = xb[PL/4 + p4];
        fx4 x2 = xb[2*(PL/4) + p4];
        float q0[NK*3];
        #pragma unroll
        for (int k = 0; k < NK*3; ++k) q0[k] = S.o.sq[k];
        fx4* ob = (fx4*)(out + (size_t)b * NK * PL);
        #pragma unroll
        for (int k = 0; k < NK; ++k) {
            fx4 o = q0[k*3+0]*x0 + q0[k*3+1]*x1 + q0[k*3+2]*x2;
            __builtin_nontemporal_store(o, ob + (size_t)k * (PL/4) + p4);
        }
        __syncthreads();                      // lq/sq dead before next tile
    }
}

extern "C" void kernel_launch(void* const* d_in, const int* in_sizes, int n_in,
                              void* d_out, int out_size, void* d_ws, size_t ws_size,
                              hipStream_t stream)
{
    const float* fm = (const float*)d_in[0];   // [8,256,64,64]
    const float* x  = (const float*)d_in[1];   // [8,3,512,512]
    const float* Wc = (const float*)d_in[2];   // [21,256]
    const float* bc = (const float*)d_in[3];   // [21]
    float* out = (float*)d_out;                // [8,21,512,512]
    float* qpart = (float*)d_ws;               // [512][64] floats = 128 KB

    void* args[] = { (void*)&fm, (void*)&Wc, (void*)&bc, (void*)&x,
                     (void*)&qpart, (void*)&out };
    hipLaunchCooperativeKernel((const void*)k_all, dim3(GRID), dim3(256),
                               args, 0, stream);
}

// Round 7
// 238.308 us; speedup vs baseline: 1.5528x; 1.5528x over previous
//
#include <hip/hip_runtime.h>
#include <math.h>

#define NB 8
#define NC 256
#define HS 64
#define WSM 64
#define HL 512
#define WL 512
#define NK 21
#define PS (HS*WSM)     /* 4096 */
#define PL (HL*WL)      /* 262144 */

#define WT_ELEMS (NK*NC)            /* 5376 */

typedef float fx4 __attribute__((ext_vector_type(4)));

// ws layout (floats):
//   qpart: [B*64][64]  (per-block q partials, padded)  off 0  size 32768
// No prep kernel: W staged per-block in LDS; qpart slots each written
// exactly once (no atomics -> no zero-init dependency).
// R6 cooperative single-kernel merge REGRESSED (370 µs: grid.sync wake cost +
// phase-2 occupancy pinned at 8 waves/CU, 1.0 TB/s). Two-kernel structure is
// the right shape; k_out needs its own high occupancy.

// fused: W-transpose staging (all waves -> LDS) + separable bilinear adjoint
// from x (waves 0-2: vertical 18-tap into LDS tmp, then horizontal 18-tap ->
// sA) + logits (4-wave c-split, W via LDS broadcast) + softmax + q-partials.
// XCD swizzle: swz=(id&7)*64+id/8 -> XCD k processes image b=k only, so its
// 3 MB x-slice stays resident in that XCD's 4 MB L2 across the ~2.2x re-read.
__global__ __launch_bounds__(256) void k_fused(
    const float* __restrict__ fm, const float* __restrict__ Wc,
    const float* __restrict__ bc, const float* __restrict__ x,
    float* __restrict__ qpart)
{
    int id = blockIdx.x;                      // 0..511
    int swz = (id & 7) * 64 + (id >> 3);
    int b = swz >> 6;
    int h = swz & 63;
    int lane = threadIdx.x & 63;
    int wv   = threadIdx.x >> 6;              // 0..3: c-slice owner
    int p = h * 64 + lane;

    __shared__ float sWt[NC*22];              // 22 KB transposed W, stride 22
    __shared__ float tmp[3][WL];              // 6 KB vertical-pass scratch
    __shared__ float sA[3][64];
    __shared__ float red[4][NK][64];          // 21.5 KB

    // all waves: stage W transposed (coalesced global read, 2-way LDS alias)
    for (int i = threadIdx.x; i < WT_ELEMS; i += 256) {
        int k = i >> 8;                       // Wc is [k][c] row-major
        int c = i & 255;
        sWt[c*22 + k] = Wc[i];
    }

    const float scale = 63.0f / 511.0f;
    const float inv_scale = 511.0f / 63.0f;

    // waves 0..2: adjoint for channel wv at small-row h
    if (wv < 3) {
        // vertical: tmp[wv][X] = sum_Y wy(h,Y) * x[b,wv,Y,X]
        int Ylo = max(0,    (int)floorf((h - 1) * inv_scale) - 1);
        int Yhi = min(HL-1, (int)ceilf ((h + 1) * inv_scale) + 1);
        const float* xc = x + (size_t)(b*3 + wv) * PL;
        fx4 acc0 = {0.f,0.f,0.f,0.f}, acc1 = {0.f,0.f,0.f,0.f};
        for (int Y = Ylo; Y <= Yhi; ++Y) {
            float fs = Y * scale;
            int i0 = (int)fs; if (i0 > HS-1) i0 = HS-1;
            float f = fs - (float)i0;
            int i1 = min(i0 + 1, HS-1);
            float wt = (i0 == h ? 1.f - f : 0.f) + (i1 == h ? f : 0.f);
            const fx4* xr = (const fx4*)(xc + (size_t)Y * WL);
            acc0 += wt * xr[lane];
            acc1 += wt * xr[lane + 64];
        }
        fx4* t4 = (fx4*)tmp[wv];
        t4[lane]      = acc0;
        t4[lane + 64] = acc1;
        // horizontal (same-wave DS ordering, no barrier needed):
        const int w_ = lane;
        int Xlo = max(0,    (int)floorf((w_ - 1) * inv_scale) - 1);
        int Xhi = min(WL-1, (int)ceilf ((w_ + 1) * inv_scale) + 1);
        float a = 0.f;
        for (int X = Xlo; X <= Xhi; ++X) {
            float fs = X * scale;
            int i0 = (int)fs; if (i0 > WSM-1) i0 = WSM-1;
            float f = fs - (float)i0;
            int i1 = min(i0 + 1, WSM-1);
            float wt = (i0 == w_ ? 1.f - f : 0.f) + (i1 == w_ ? f : 0.f);
            a = fmaf(wt, tmp[wv][X], a);
        }
        sA[wv][lane] = a;
    }

    __syncthreads();                          // sWt ready (and sA ordered)

    // all 4 waves: logits partial over this wave's 64-channel slice.
    // unroll 16: fm loop is HBM-latency-bound at 8 waves/CU; 16 loads in
    // flight per wave doubles outstanding bytes toward BW saturation.
    float part[NK];
    #pragma unroll
    for (int k = 0; k < NK; ++k) part[k] = 0.f;

    const float* fmb = fm + (size_t)b * NC * PS + (size_t)(wv * 64) * PS + p;
    #pragma unroll 16
    for (int cc = 0; cc < 64; ++cc) {
        float v = __builtin_nontemporal_load(fmb + (size_t)cc * PS);
        const float* w = sWt + (wv * 64 + cc) * 22;  // uniform -> LDS broadcast
        #pragma unroll
        for (int k = 0; k < NK; ++k) part[k] = fmaf(v, w[k], part[k]);
    }

    #pragma unroll
    for (int k = 0; k < NK; ++k) red[wv][k][lane] = part[k];
    __syncthreads();

    // every wave reconstructs the full logits (redundant but parallel-free)
    float logit[NK];
    #pragma unroll
    for (int k = 0; k < NK; ++k)
        logit[k] = bc[k] + ((red[0][k][lane] + red[1][k][lane])
                          + (red[2][k][lane] + red[3][k][lane]));

    float m = logit[0];
    #pragma unroll
    for (int k = 1; k < NK; ++k) m = fmaxf(m, logit[k]);
    float s = 0.f;
    #pragma unroll
    for (int k = 0; k < NK; ++k) { logit[k] = __expf(logit[k] - m); s += logit[k]; }
    float inv = 1.f / s;

    float a0 = sA[0][lane], a1 = sA[1][lane], a2 = sA[2][lane];

    // q-partials: wave wv owns k = wv, wv+4, ...; each slot written once.
    float* qb = qpart + (size_t)(b*64 + h) * 64;
    for (int k = wv; k < NK; k += 4) {
        float sv = logit[k] * inv;
        float r0 = sv * a0, r1 = sv * a1, r2 = sv * a2;
        #pragma unroll
        for (int off = 32; off; off >>= 1) {
            r0 += __shfl_down(r0, off);
            r1 += __shfl_down(r1, off);
            r2 += __shfl_down(r2, off);
        }
        if (lane == 0) {
            qb[k*3 + 0] = r0;
            qb[k*3 + 1] = r1;
            qb[k*3 + 2] = r2;
        }
    }
}

// out[b,k,p] = sum_c x[b,c,p] * q[b,k,c]/PL, with q reduced from qpart
// (64 slots/image, L2/L3-resident, coalesced into LDS then summed).
__global__ __launch_bounds__(256) void k_out(
    const float* __restrict__ x, const float* __restrict__ qpart,
    float* __restrict__ out)
{
    __shared__ float lq[64*64];               // 16 KB
    __shared__ float sq[NK*3];
    int tid = threadIdx.x;
    int b = blockIdx.y;

    const fx4* qp4 = (const fx4*)(qpart + (size_t)b * 64 * 64);
    fx4* lq4 = (fx4*)lq;
    #pragma unroll
    for (int j = 0; j < 4; ++j) lq4[tid + j*256] = qp4[tid + j*256];
    __syncthreads();
    if (tid < NK*3) {
        float s = 0.f;
        for (int j = 0; j < 64; ++j) s += lq[j*64 + tid];
        sq[tid] = s * (1.0f / (float)PL);
    }
    __syncthreads();

    int p4 = blockIdx.x * 256 + tid;          // 65536 fx4 per image
    const fx4* xb = (const fx4*)(x + (size_t)b * 3 * PL);
    fx4 x0 = xb[p4];
    fx4 x1 = xb[PL/4 + p4];
    fx4 x2 = xb[2*(PL/4) + p4];
    fx4* ob = (fx4*)(out + (size_t)b * NK * PL);
    #pragma unroll
    for (int k = 0; k < NK; ++k) {
        fx4 o = sq[k*3+0]*x0 + sq[k*3+1]*x1 + sq[k*3+2]*x2;
        __builtin_nontemporal_store(o, ob + (size_t)k * (PL/4) + p4);
    }
}

extern "C" void kernel_launch(void* const* d_in, const int* in_sizes, int n_in,
                              void* d_out, int out_size, void* d_ws, size_t ws_size,
                              hipStream_t stream)
{
    const float* fm = (const float*)d_in[0];   // [8,256,64,64]
    const float* x  = (const float*)d_in[1];   // [8,3,512,512]
    const float* Wc = (const float*)d_in[2];   // [21,256]
    const float* bc = (const float*)d_in[3];   // [21]
    float* out = (float*)d_out;                // [8,21,512,512]

    float* qpart = (float*)d_ws;              // [512][64] floats = 128 KB

    k_fused<<<NB*HS, 256, 0, stream>>>(fm, Wc, bc, x, qpart);
    k_out<<<dim3(PL/4/256, NB), 256, 0, stream>>>(x, qpart, out);
}